// Round 8
// baseline (620.683 us; speedup 1.0000x reference)
//
#include <hip/hip_runtime.h>
#include <math.h>

#define BATCH  32
#define NPTS   8192
#define NGROUP 512
#define MSIZE  32

#define FPS_THREADS 256          // r8 probe: 4 waves (was 512/8) — halves atomic
                                 // depth + barrier skew; per-SIMD issue invariant
#define SXYZ_FLOATS (NPTS * 3)
#define DYN_LDS_BYTES (SXYZ_FLOATS * 4)

typedef float v2f __attribute__((ext_vector_type(2)));

// ---- DPP helpers (CTRL compile-time const) --------------------------------
// f32 max: bound_ctrl=true -> masked-off lanes read 0; fmax(x,0)=x for x>=0.
template<int CTRL>
__device__ __forceinline__ float dpp_max_f32(float x) {
    int o = __builtin_amdgcn_update_dpp(0, __float_as_int(x), CTRL, 0xF, 0xF, true);
    float f = __int_as_float(o);
    return x > f ? x : f;
}
template<int CTRL>
__device__ __forceinline__ unsigned dpp_min_u32_full(unsigned x) {
    unsigned o = (unsigned)__builtin_amdgcn_update_dpp(0, (int)x, CTRL, 0xF, 0xF, true);
    return o < x ? o : x;
}

// ---------------------------------------------------------------------------
// FPS: one block/batch, 256 threads (4 waves, 1/SIMD), 32 pts/thread as v2f
// pairs (packed f32 math, per-element bit-exact numpy order: (dx^2+dy^2)+dz^2,
// contract off). Ownership CONTIGUOUS: thread t owns [32t, 32t+32) so
// (wave,lane,j) lexicographic == global index order. Per step, ONE barrier:
//   dist update -> per-thread max m_t -> 6-stage f32 DPP -> wmax=readlane63
//   -> ballot(m_t==wmax) -> lowest candidate lane l (s_ff1)
//   -> all lanes: lj = lowest j with d[j]==wmax (cmp/sel chain); idx=(t<<5)|lj
//   -> widx = readlane(idx, l)   [wave winner, exact first-occurrence]
//   -> lane63: ds_max_u64(gkey[g%3], (wmaxbits<<32)|~widx)  [4 atomics deep]
//   -> barrier -> all read gkey (broadcast b64) -> fi = ~lo32.
// gkey triple-buffered; slot (g+1)%3 reset in step g (race-free). Exact
// np.argmax first-occurrence semantics incl. ties.
// History: r1 (post-barrier slot tree), r3 (tie-tree/store-hoist), r4 (4-slot
// atomic), r6/r7 (fusion) all neutral-to-negative. This probes the LAST
// untouched axis: wave count (serial tail ~ atomic depth + barrier skew).
// ---------------------------------------------------------------------------
__global__ __launch_bounds__(FPS_THREADS, 1)
void fps_kernel(const float* __restrict__ xyz,
                float* __restrict__ out_center,
                float* __restrict__ out_fps)
{
#pragma clang fp contract(off)
    extern __shared__ float sxyz[];                        // [24576]
    __shared__ unsigned long long gkey[3];

    const int b    = blockIdx.x;
    const int t    = threadIdx.x;
    const int lane = t & 63;
    const float* bp = xyz + (size_t)b * NPTS * 3;
    const float4* bp4 = reinterpret_cast<const float4*>(bp);
    float4* s4 = reinterpret_cast<float4*>(sxyz);

    // contiguous ownership: thread t owns points 32t..32t+31 (96 floats,
    // 24 float4). Stage into LDS with the same reads; direct compile-time
    // placement into v2f slots (same element mapping as r0's f[] repack).
    v2f px2[16], py2[16], pz2[16], dist2[16];
    #pragma unroll
    for (int j = 0; j < 16; ++j) dist2[j] = (v2f){INFINITY, INFINITY};
    #pragma unroll
    for (int q = 0; q < 24; ++q) {
        float4 v = bp4[t * 24 + q];
        s4[t * 24 + q] = v;
        const float vv[4] = {v.x, v.y, v.z, v.w};
        #pragma unroll
        for (int e = 0; e < 4; ++e) {
            const int n  = q * 4 + e;      // 0..95, compile-time
            const int j2 = n / 3;          // point within thread (0..31)
            const int c  = n % 3;          // coord
            const int h  = j2 >> 1;        // v2 slot
            const float val = vv[e];
            if (c == 0)      { if (j2 & 1) px2[h].y = val; else px2[h].x = val; }
            else if (c == 1) { if (j2 & 1) py2[h].y = val; else py2[h].x = val; }
            else             { if (j2 & 1) pz2[h].y = val; else pz2[h].x = val; }
        }
    }
    if (t == 0) { gkey[0] = 0; gkey[1] = 0; gkey[2] = 0; }
    __syncthreads();   // sxyz + gkey visible

    if (t == 0) {
        out_fps[(size_t)b * NGROUP] = 0.0f;
        out_center[(size_t)(b * NGROUP) * 3 + 0] = sxyz[0];
        out_center[(size_t)(b * NGROUP) * 3 + 1] = sxyz[1];
        out_center[(size_t)(b * NGROUP) * 3 + 2] = sxyz[2];
    }

    int last = 0;
    for (int g = 1; g < NGROUP; ++g) {
        const int slot = g % 3;
        const int nxt  = (g + 1) % 3;
        float lx = sxyz[last*3 + 0];     // broadcast LDS reads
        float ly = sxyz[last*3 + 1];
        float lz = sxyz[last*3 + 2];

        // packed dist update: per element (dx*dx + dy*dy) + dz*dz, then min
        #pragma unroll
        for (int j = 0; j < 16; ++j) {
            v2f dx = px2[j] - lx;
            v2f dy = py2[j] - ly;
            v2f dz = pz2[j] - lz;
            v2f t1 = dx * dx;
            v2f t2 = dy * dy;
            v2f t3 = dz * dz;
            v2f s  = t1 + t2;
            v2f d  = s + t3;
            dist2[j] = __builtin_elementwise_min(dist2[j], d);
        }
        // per-thread max (exact, order-free): 15-op pk tree + final fmax
        v2f a0 = __builtin_elementwise_max(dist2[0],  dist2[1]);
        v2f a1 = __builtin_elementwise_max(dist2[2],  dist2[3]);
        v2f a2 = __builtin_elementwise_max(dist2[4],  dist2[5]);
        v2f a3 = __builtin_elementwise_max(dist2[6],  dist2[7]);
        v2f a4 = __builtin_elementwise_max(dist2[8],  dist2[9]);
        v2f a5 = __builtin_elementwise_max(dist2[10], dist2[11]);
        v2f a6 = __builtin_elementwise_max(dist2[12], dist2[13]);
        v2f a7 = __builtin_elementwise_max(dist2[14], dist2[15]);
        v2f b0 = __builtin_elementwise_max(a0, a1);
        v2f b1 = __builtin_elementwise_max(a2, a3);
        v2f b2 = __builtin_elementwise_max(a4, a5);
        v2f b3 = __builtin_elementwise_max(a6, a7);
        v2f c0 = __builtin_elementwise_max(b0, b1);
        v2f c1 = __builtin_elementwise_max(b2, b3);
        v2f d0 = __builtin_elementwise_max(c0, c1);
        float m_t = fmaxf(d0.x, d0.y);

        // wave max via DPP -> wmax (uniform, sgpr)
        float m = m_t;
        m = dpp_max_f32<0xB1>(m);     // quad_perm xor1
        m = dpp_max_f32<0x4E>(m);     // quad_perm xor2
        m = dpp_max_f32<0x141>(m);    // row_half_mirror
        m = dpp_max_f32<0x140>(m);    // row_mirror
        m = dpp_max_f32<0x142>(m);    // row_bcast15
        m = dpp_max_f32<0x143>(m);    // row_bcast31
        float wmax = __int_as_float(__builtin_amdgcn_readlane(__float_as_int(m), 63));

        // lowest candidate lane (contiguous ownership => lane order = idx order)
        unsigned long long mask = __ballot(m_t == wmax);
        int l = __ffsll((long long)mask) - 1;

        // each lane: lowest j with d[j]==wmax (descending select chain;
        // pre-barrier tail, proven skew-hidden in r3)
        unsigned lj = 0;
        #pragma unroll
        for (int j = 31; j >= 0; --j) {
            float dj = (j & 1) ? dist2[j >> 1].y : dist2[j >> 1].x;
            lj = (dj == wmax) ? (unsigned)j : lj;
        }
        unsigned idx = ((unsigned)t << 5) | lj;
        unsigned widx = (unsigned)__builtin_amdgcn_readlane((int)idx, l);

        if (lane == 63) {
            unsigned long long key =
                (((unsigned long long)__float_as_uint(wmax)) << 32) | (unsigned)~widx;
            atomicMax(&gkey[slot], key);
            if (t == 63) gkey[nxt] = 0;   // reset slot for step g+1 (pre-barrier)
        }
        __syncthreads();                  // the ONE barrier

        unsigned long long kq = gkey[slot];   // broadcast b64 read
        int fi = (int)(~(unsigned)kq);
        last = fi;
        if (t == 0) {
            out_fps[(size_t)b * NGROUP + g] = (float)fi;
            out_center[((size_t)(b * NGROUP + g)) * 3 + 0] = sxyz[fi*3 + 0];
            out_center[((size_t)(b * NGROUP + g)) * 3 + 1] = sxyz[fi*3 + 1];
            out_center[((size_t)(b * NGROUP + g)) * 3 + 2] = sxyz[fi*3 + 2];
        }
    }
}

// ---------------------------------------------------------------------------
// kNN: EXACT round-0 kernel (113 µs). One wave/group, max occupancy. All
// alternatives measured worse or neutral: LDS-resident (r1), CPW=4 (r2),
// prefetch pipeline (r4), DPP-only reduce (r5).
// ---------------------------------------------------------------------------
__global__ __launch_bounds__(256)
void knn_kernel(const float* __restrict__ xyz,
                const float* __restrict__ center,
                float* __restrict__ out_nbhd)
{
    const int lane = threadIdx.x & 63;
    const int gid  = blockIdx.x * 4 + (threadIdx.x >> 6);   // 0..16383
    const int b    = gid >> 9;
    const float* bp = xyz + (size_t)b * NPTS * 3;
    const float4* bp4 = reinterpret_cast<const float4*>(bp);

    const float cx = center[(size_t)gid*3+0];
    const float cy = center[(size_t)gid*3+1];
    const float cz = center[(size_t)gid*3+2];

    unsigned kl[4];
    #pragma unroll
    for (int k = 0; k < 4; ++k) kl[k] = 0xFFFFFFFFu;

    for (int c = 0; c < 32; ++c) {
        int f4 = c * 192 + lane * 3;
        float4 a  = bp4[f4+0];
        float4 bq = bp4[f4+1];
        float4 cq = bp4[f4+2];
        unsigned p0 = (unsigned)(c * 256 + lane * 4);
        v2f xA = (v2f){a.x,  a.w},  yA = (v2f){a.y,  bq.x}, zA = (v2f){a.z,  bq.y};
        v2f xB = (v2f){bq.z, cq.y}, yB = (v2f){bq.w, cq.z}, zB = (v2f){cq.x, cq.w};
        v2f dxA = xA - cx, dyA = yA - cy, dzA = zA - cz;
        v2f dxB = xB - cx, dyB = yB - cy, dzB = zB - cz;
        v2f dA = dxA*dxA + dyA*dyA + dzA*dzA;
        v2f dB = dxB*dxB + dyB*dyB + dzB*dzB;
        float ds[4] = {dA.x, dA.y, dB.x, dB.y};
        #pragma unroll
        for (int k = 0; k < 4; ++k) {
            unsigned key = (__float_as_uint(ds[k]) & 0xFFFFE000u) | (p0 + k);
            if (key < kl[3]) {
                kl[3] = key;
                #pragma unroll
                for (int q = 3; q > 0; --q) {
                    if (kl[q] < kl[q-1]) {
                        unsigned tk = kl[q]; kl[q] = kl[q-1]; kl[q-1] = tk;
                    }
                }
            }
        }
    }

    int keep = 0;
    #pragma unroll 1
    for (int r = 0; r < MSIZE; ++r) {
        unsigned k = kl[0];
        k = dpp_min_u32_full<0xB1>(k);     // xor1
        k = dpp_min_u32_full<0x4E>(k);     // xor2
        k = dpp_min_u32_full<0x141>(k);    // half mirror
        k = dpp_min_u32_full<0x140>(k);    // mirror -> rows of 16 uniform
        {
            unsigned o = __shfl_xor(k, 16);
            k = o < k ? o : k;
            o = __shfl_xor(k, 32);
            k = o < k ? o : k;
        }
        if (lane == r) keep = (int)(k & 0x1FFFu);
        if (kl[0] == k) {                   // unique (idx embedded)
            kl[0] = kl[1]; kl[1] = kl[2]; kl[2] = kl[3];
            kl[3] = 0xFFFFFFFFu;
        }
    }

    if (lane < MSIZE) {
        size_t o = ((size_t)gid * MSIZE + lane) * 3;
        float x = bp[keep*3+0], y = bp[keep*3+1], z = bp[keep*3+2];
        out_nbhd[o+0] = x - cx;
        out_nbhd[o+1] = y - cy;
        out_nbhd[o+2] = z - cz;
    }
}

// ---------------------------------------------------------------------------
extern "C" void kernel_launch(void* const* d_in, const int* in_sizes, int n_in,
                              void* d_out, int out_size, void* d_ws, size_t ws_size,
                              hipStream_t stream)
{
    const float* xyz = (const float*)d_in[0];
    float* out        = (float*)d_out;
    float* out_nbhd   = out;                                    // 32*512*32*3
    float* out_center = out + (size_t)BATCH*NGROUP*MSIZE*3;     // 32*512*3
    float* out_fps    = out_center + (size_t)BATCH*NGROUP*3;    // 32*512

    hipFuncSetAttribute(reinterpret_cast<const void*>(fps_kernel),
                        hipFuncAttributeMaxDynamicSharedMemorySize,
                        DYN_LDS_BYTES);

    fps_kernel<<<dim3(BATCH), dim3(FPS_THREADS), DYN_LDS_BYTES, stream>>>(xyz, out_center, out_fps);
    knn_kernel<<<dim3(BATCH*NGROUP/4), dim3(256), 0, stream>>>(xyz, out_center, out_nbhd);
}